// Round 1
// baseline (586.574 us; speedup 1.0000x reference)
//
#include <hip/hip_runtime.h>
#include <stdint.h>

// Problem constants
#define BB 64
#define VV 2000
#define DD 16
#define CI 64
#define CO 64
#define IO 4096   // CI*CO
#define BI 4096   // BB*CI

// ws layout (float offsets)
#define WS_INV  0                       // 1 float: 1/frob_norm
#define WS_WAB  16                      // uint2 [DD][IO]: packed bf16 {wA(re,im), wB(re,im)}
#define WS_Z    (16 + DD*IO*2)          // float2 [DD][BI]: (Z_re, Z_im)
// total = 16 + 131072 + 131072 = 262160 floats ~= 1.05 MB

__device__ __forceinline__ uint32_t f2bf(float f) {
  uint32_t u = __float_as_uint(f);
  return (u + 0x7FFFu + ((u >> 16) & 1u)) >> 16;   // RNE
}
__device__ __forceinline__ uint32_t packbf2(float re, float im) {
  return f2bf(re) | (f2bf(im) << 16);
}
__device__ __forceinline__ float bflo(uint32_t p) { return __uint_as_float(p << 16); }
__device__ __forceinline__ float bfhi(uint32_t p) { return __uint_as_float(p & 0xFFFF0000u); }

// ---------------------------------------------------------------------------
// K1: inv_norm = 1/||E^H E||_F  (== 1/||E E^H||_F, trace identity)
// one block, 256 threads, thread t owns Gram entry (d,e)
__global__ void k_norm(const float* __restrict__ ne_re, const float* __restrict__ ne_im,
                       float* __restrict__ ws) {
  int t = threadIdx.x;
  int d = t >> 4, e = t & 15;
  float gr = 0.f, gi = 0.f;
  for (int v = 0; v < VV; ++v) {
    float ar = ne_re[v*DD + d], ai = ne_im[v*DD + d];
    float br = ne_re[v*DD + e], bi = ne_im[v*DD + e];
    // conj(a)*b
    gr += ar*br + ai*bi;
    gi += ar*bi - ai*br;
  }
  __shared__ float red[256];
  red[t] = gr*gr + gi*gi;
  __syncthreads();
  for (int k = 128; k > 0; k >>= 1) {
    if (t < k) red[t] += red[t + k];
    __syncthreads();
  }
  if (t == 0) ws[WS_INV] = 1.0f / sqrtf(red[0]);
}

// ---------------------------------------------------------------------------
// K2: combined pools wA = w0 - w2, wB = w1 + 2*w2 (complex), packed bf16
__global__ void k_prep(const float* __restrict__ w_re, const float* __restrict__ w_im,
                       float* __restrict__ ws) {
  int idx = blockIdx.x * 256 + threadIdx.x;   // d*IO + io
  int d = idx >> 12, io = idx & (IO - 1);
  int base = d * (3 * IO) + io;               // w[d,k,i,o], k stride = IO
  float w0r = w_re[base], w1r = w_re[base + IO], w2r = w_re[base + 2*IO];
  float w0i = w_im[base], w1i = w_im[base + IO], w2i = w_im[base + 2*IO];
  uint2 pk;
  pk.x = packbf2(w0r - w2r, w0i - w2i);
  pk.y = packbf2(w1r + 2.f*w2r, w1i + 2.f*w2i);
  reinterpret_cast<uint2*>(ws + WS_WAB)[idx] = pk;
}

// ---------------------------------------------------------------------------
// K3a: zero the Z accumulator (ws is poisoned 0xAA before every launch)
__global__ void k_zero(float* __restrict__ ws) {
  int idx = blockIdx.x * 256 + threadIdx.x;   // 512*256 = 131072
  ws[WS_Z + idx] = 0.f;
}

// K3b: Z[d,b,i] = sum_v conj(ne[v,d]) * x[b,v,i]   (x real)
// grid 256 = (b:64) x (vchunk:4), 1024 threads = (d:16) x (i:64)
__global__ void k_z(const float* __restrict__ x, const float* __restrict__ ne_re,
                    const float* __restrict__ ne_im, float* __restrict__ ws) {
  int b = blockIdx.x >> 2, c = blockIdx.x & 3;
  int t = threadIdx.x;
  int i = t & 63, d = t >> 6;
  const float* xp = x + (size_t)b * (VV * CI);
  float zr = 0.f, zi = 0.f;
  int v0 = c * 500, v1 = v0 + 500;
  for (int v = v0; v < v1; ++v) {
    float xv = xp[v*CI + i];
    float nr = ne_re[v*DD + d];
    float ni = ne_im[v*DD + d];
    zr += nr * xv;
    zi -= ni * xv;   // conj
  }
  float* zp = ws + WS_Z + (size_t)(d * BI + b * CI + i) * 2;
  atomicAdd(zp, zr);
  atomicAdd(zp + 1, zi);
}

// ---------------------------------------------------------------------------
// K4: per-node fused epilogue. Block = node u, 512 threads (8 waves).
//   phase B: A[u] = sum_d ne[u,d]*wA[d], Bw[u] = sum_d ne[u,d]*wB[d]  -> LDS bf16
//   phase C: y[b,u,i] = invn * sum_d ne[u,d]*Z[d,b,i]                 -> LDS bf16
//   phase D: out[b,u,o] = sum_i x*A + y*Bw + bias[u,o]  (fp32 accum)
__global__ void __launch_bounds__(512, 2)
k_final(const float* __restrict__ x, const float* __restrict__ ne_re,
        const float* __restrict__ ne_im, const float* __restrict__ b_re,
        const float* __restrict__ b_im, const float* __restrict__ ws,
        float* __restrict__ out) {
  int u = blockIdx.x;
  int t = threadIdx.x;
  __shared__ uint32_t sA[IO];   // packed bf16 (A_re, A_im), [i][o]
  __shared__ uint32_t sB[IO];   // packed bf16 (B_re, B_im), [i][o]
  __shared__ uint32_t sY[BI];   // packed bf16 (y_re, y_im), [b][i]
  __shared__ float    sX[BI];   // fp32 x, [b][i]

  float ner[DD], nei[DD];
  #pragma unroll
  for (int d = 0; d < DD; ++d) {
    ner[d] = ne_re[u*DD + d];
    nei[d] = ne_im[u*DD + d];
  }
  float invn = ws[WS_INV];

  // phase B
  const uint2* wab = reinterpret_cast<const uint2*>(ws + WS_WAB);
  #pragma unroll 2
  for (int j = 0; j < 8; ++j) {
    int io = j*512 + t;
    float ar = 0.f, ai = 0.f, br = 0.f, bi = 0.f;
    #pragma unroll
    for (int d = 0; d < DD; ++d) {
      uint2 w = wab[d*IO + io];
      float war = bflo(w.x), wai = bfhi(w.x);
      float wbr = bflo(w.y), wbi = bfhi(w.y);
      ar += ner[d]*war - nei[d]*wai;
      ai += ner[d]*wai + nei[d]*war;
      br += ner[d]*wbr - nei[d]*wbi;
      bi += ner[d]*wbi + nei[d]*wbr;
    }
    sA[io] = packbf2(ar, ai);
    sB[io] = packbf2(br, bi);
  }

  // phase C
  const float2* zp = reinterpret_cast<const float2*>(ws + WS_Z);
  #pragma unroll 2
  for (int j = 0; j < 8; ++j) {
    int bi_ = j*512 + t;                   // b*CI + i
    float yr = 0.f, yi = 0.f;
    #pragma unroll
    for (int d = 0; d < DD; ++d) {
      float2 z = zp[d*BI + bi_];
      yr += ner[d]*z.x - nei[d]*z.y;
      yi += ner[d]*z.y + nei[d]*z.x;
    }
    sY[bi_] = packbf2(yr * invn, yi * invn);
    int b = bi_ >> 6, i = bi_ & 63;
    sX[bi_] = x[((size_t)b*VV + u)*CI + i];
  }
  __syncthreads();

  // phase D: wave bg owns b in [bg*8, bg*8+8), lane owns o
  int o = t & 63, bg = t >> 6;
  float biasr = 0.f, biasi = 0.f;
  #pragma unroll
  for (int d = 0; d < DD; ++d) {
    float pr = b_re[d*CO + o], pi = b_im[d*CO + o];
    biasr += ner[d]*pr - nei[d]*pi;
    biasi += ner[d]*pi + nei[d]*pr;
  }
  float accr[8], acci[8];
  #pragma unroll
  for (int j = 0; j < 8; ++j) { accr[j] = biasr; acci[j] = biasi; }

  #pragma unroll 4
  for (int i = 0; i < CI; ++i) {
    uint32_t pa = sA[i*CO + o];     // 2-way bank alias: free
    uint32_t pb = sB[i*CO + o];
    float ar = bflo(pa), ai = bfhi(pa);
    float br = bflo(pb), bi2 = bfhi(pb);
    #pragma unroll
    for (int j = 0; j < 8; ++j) {
      int b = bg*8 + j;
      float xv = sX[b*CI + i];      // wave-uniform: LDS broadcast
      uint32_t py = sY[b*CI + i];
      float yr = bflo(py), yi = bfhi(py);
      accr[j] += xv*ar + yr*br - yi*bi2;
      acci[j] += xv*ai + yr*bi2 + yi*br;
    }
  }

  float2* out2 = reinterpret_cast<float2*>(out);   // interleaved (re, im)
  #pragma unroll
  for (int j = 0; j < 8; ++j) {
    int b = bg*8 + j;
    out2[((size_t)b*VV + u)*CO + o] = make_float2(accr[j], acci[j]);
  }
}

// ---------------------------------------------------------------------------
extern "C" void kernel_launch(void* const* d_in, const int* in_sizes, int n_in,
                              void* d_out, int out_size, void* d_ws, size_t ws_size,
                              hipStream_t stream) {
  (void)in_sizes; (void)n_in; (void)out_size; (void)ws_size;
  const float* x     = (const float*)d_in[0];
  const float* ne_re = (const float*)d_in[1];
  const float* ne_im = (const float*)d_in[2];
  const float* w_re  = (const float*)d_in[3];
  const float* w_im  = (const float*)d_in[4];
  const float* b_re  = (const float*)d_in[5];
  const float* b_im  = (const float*)d_in[6];
  float* out = (float*)d_out;
  float* ws  = (float*)d_ws;

  k_norm<<<dim3(1),    dim3(256),  0, stream>>>(ne_re, ne_im, ws);
  k_prep<<<dim3(256),  dim3(256),  0, stream>>>(w_re, w_im, ws);
  k_zero<<<dim3(512),  dim3(256),  0, stream>>>(ws);
  k_z   <<<dim3(256),  dim3(1024), 0, stream>>>(x, ne_re, ne_im, ws);
  k_final<<<dim3(VV),  dim3(512),  0, stream>>>(x, ne_re, ne_im, b_re, b_im, ws, out);
}

// Round 2
// 355.399 us; speedup vs baseline: 1.6505x; 1.6505x over previous
//
#include <hip/hip_runtime.h>
#include <stdint.h>

// Problem constants
#define BB 64
#define VV 2000
#define DD 16
#define CI 64
#define CO 64
#define IO 4096   // CI*CO
#define BI 4096   // BB*CI

// ws layout (float/dword offsets)
#define WS_INV   0
#define WS_GRAM  8                         // 256 x (gr,gi) = 512 floats
#define WS_Z     1024                      // float2[16][4096] = 131072 floats
#define WS_WAB   (1024 + 131072)           // uint2[16][64][64]  wab_t[d][o][i], 131072 dwords
#define WS_Y     (1024 + 131072 + 131072)  // uint32[2000][4096] packed bf16 (yr,yi)
// total = 8,455,168 dwords ~= 33.8 MB

typedef __attribute__((ext_vector_type(8))) short short8;
typedef __attribute__((ext_vector_type(4))) float f32x4;

__device__ __forceinline__ uint32_t f2bf(float f) {
  uint32_t u = __float_as_uint(f);
  return (u + 0x7FFFu + ((u >> 16) & 1u)) >> 16;   // RNE
}
__device__ __forceinline__ uint32_t packbf2(float re, float im) {
  return f2bf(re) | (f2bf(im) << 16);
}
__device__ __forceinline__ float bflo(uint32_t p) { return __uint_as_float(p << 16); }
__device__ __forceinline__ float bfhi(uint32_t p) { return __uint_as_float(p & 0xFFFF0000u); }

// ---------------------------------------------------------------------------
// K0: zero INV+GRAM+Z region: floats [0, 132096) = 129 blocks * 256 threads * 4
__global__ void k_zero(float* __restrict__ ws) {
  int idx4 = blockIdx.x * 256 + threadIdx.x;
  reinterpret_cast<float4*>(ws)[idx4] = make_float4(0.f, 0.f, 0.f, 0.f);
}

// K1a: partial Gram G[d,e] = sum_v conj(E[v,d])*E[v,e], 8 blocks x 250 v
__global__ void k_norm1(const float* __restrict__ ne_re, const float* __restrict__ ne_im,
                        float* __restrict__ ws) {
  int t = threadIdx.x;
  int d = t >> 4, e = t & 15;
  int v0 = blockIdx.x * 250;
  float gr = 0.f, gi = 0.f;
  for (int v = v0; v < v0 + 250; ++v) {
    float ar = ne_re[v*DD + d], ai = ne_im[v*DD + d];
    float br = ne_re[v*DD + e], bi = ne_im[v*DD + e];
    gr += ar*br + ai*bi;
    gi += ar*bi - ai*br;
  }
  atomicAdd(ws + WS_GRAM + 2*t,     gr);
  atomicAdd(ws + WS_GRAM + 2*t + 1, gi);
}

// K1b: inv_norm = 1/sqrt(sum |G|^2)
__global__ void k_norm2(float* __restrict__ ws) {
  int t = threadIdx.x;
  float gr = ws[WS_GRAM + 2*t], gi = ws[WS_GRAM + 2*t + 1];
  __shared__ float red[256];
  red[t] = gr*gr + gi*gi;
  __syncthreads();
  for (int k = 128; k > 0; k >>= 1) {
    if (t < k) red[t] += red[t + k];
    __syncthreads();
  }
  if (t == 0) ws[WS_INV] = 1.0f / sqrtf(red[0]);
}

// ---------------------------------------------------------------------------
// K2: combined pools wA = w0 - w2, wB = w1 + 2*w2 (complex), packed bf16,
//     TRANSPOSED layout wab_t[d][o][i] so k_final phase-B reads are coalesced
//     with lanes on i.
__global__ void k_prep(const float* __restrict__ w_re, const float* __restrict__ w_im,
                       float* __restrict__ ws) {
  int idx = blockIdx.x * 256 + threadIdx.x;   // = d*4096 + o*64 + i (write-linear)
  int i = idx & 63, o = (idx >> 6) & 63, d = idx >> 12;
  int base = d * (3 * IO) + i * CO + o;       // w[d,k,i,o], k stride = IO
  float w0r = w_re[base], w1r = w_re[base + IO], w2r = w_re[base + 2*IO];
  float w0i = w_im[base], w1i = w_im[base + IO], w2i = w_im[base + 2*IO];
  uint2 pk;
  pk.x = packbf2(w0r - w2r, w0i - w2i);
  pk.y = packbf2(w1r + 2.f*w2r, w1i + 2.f*w2i);
  reinterpret_cast<uint2*>(ws + WS_WAB)[idx] = pk;
}

// ---------------------------------------------------------------------------
// K3: Z[d,b,i] = sum_v conj(ne[v,d]) * x[b,v,i]
// grid 512 = (b:64) x (vchunk:8), 1024 threads = (d:16) x (i:64)
__global__ void k_z(const float* __restrict__ x, const float* __restrict__ ne_re,
                    const float* __restrict__ ne_im, float* __restrict__ ws) {
  int b = blockIdx.x >> 3, c = blockIdx.x & 7;
  int t = threadIdx.x;
  int i = t & 63, d = t >> 6;
  const float* xp = x + (size_t)b * (VV * CI);
  float zr = 0.f, zi = 0.f;
  int v0 = c * 250, v1 = v0 + 250;
  for (int v = v0; v < v1; ++v) {
    float xv = xp[v*CI + i];        // 16 threads share addr -> L1 broadcast
    float nr = ne_re[v*DD + d];     // wave-uniform
    float ni = ne_im[v*DD + d];
    zr += nr * xv;
    zi -= ni * xv;                  // conj
  }
  float* zp = ws + WS_Z + (size_t)(d * BI + b * CI + i) * 2;
  atomicAdd(zp, zr);
  atomicAdd(zp + 1, zi);
}

// ---------------------------------------------------------------------------
// K4: Y[u][bi] = packed bf16 (yr, yi), y = invn * sum_d ne[u,d]*Z[d,bi]
// grid (500, 16), block 256: thread = (u_local:4) x (bi_lane:64), 4 bi each
__global__ void k_y(const float* __restrict__ ne_re, const float* __restrict__ ne_im,
                    float* __restrict__ ws) {
  int t = threadIdx.x;
  int u = blockIdx.x * 4 + (t >> 6);
  int bi0 = blockIdx.y * 256 + (t & 63);
  float invn = ws[WS_INV];
  const float2* zp = reinterpret_cast<const float2*>(ws + WS_Z);
  float yr[4] = {0.f,0.f,0.f,0.f}, yi[4] = {0.f,0.f,0.f,0.f};
  #pragma unroll
  for (int d = 0; d < DD; ++d) {
    float nr = ne_re[u*DD + d];
    float ni = ne_im[u*DD + d];
    #pragma unroll
    for (int s = 0; s < 4; ++s) {
      float2 z = zp[d*BI + bi0 + s*64];
      yr[s] += nr*z.x - ni*z.y;
      yi[s] += nr*z.y + ni*z.x;
    }
  }
  uint32_t* Yp = reinterpret_cast<uint32_t*>(ws + WS_Y);
  #pragma unroll
  for (int s = 0; s < 4; ++s)
    Yp[(size_t)u*BI + bi0 + s*64] = packbf2(yr[s]*invn, yi[s]*invn);
}

// ---------------------------------------------------------------------------
// K5: per-node fused kernel, MFMA phase D.
//   LDS: sW[128][200] bf16 : W2T[o2][k] = [Ar,Br,-Bi ; Ai,Bi,Br]
//        sU[ 64][200] bf16 : U[b][k]    = [x, yr, yi]
//   Out[b][o2] (M=64,N=128,K=192) = U * W2T^T via 16x16x32 bf16 MFMA.
#define WPITCH 200
__global__ void __launch_bounds__(512, 4)
k_final(const float* __restrict__ x, const float* __restrict__ ne_re,
        const float* __restrict__ ne_im, const float* __restrict__ b_re,
        const float* __restrict__ b_im, const float* __restrict__ ws,
        float* __restrict__ out) {
  int u = blockIdx.x;
  int t = threadIdx.x;
  __shared__ __align__(16) unsigned short sW[128 * WPITCH];
  __shared__ __align__(16) unsigned short sU[64 * WPITCH];

  float ner[DD], nei[DD];
  #pragma unroll
  for (int d = 0; d < DD; ++d) {
    ner[d] = ne_re[u*DD + d];
    nei[d] = ne_im[u*DD + d];
  }

  // ---- phase B: per-node weights -> sW (lanes on i => contiguous LDS rows)
  const uint2* wab = reinterpret_cast<const uint2*>(ws + WS_WAB);
  int iB = t & 63, og = t >> 6;                // og in [0,8)
  #pragma unroll 2
  for (int j = 0; j < 8; ++j) {
    int o = j*8 + og;
    float ar = 0.f, ai = 0.f, br = 0.f, bi = 0.f;
    #pragma unroll
    for (int d = 0; d < DD; ++d) {
      uint2 w = wab[d*IO + o*CI + iB];
      float war = bflo(w.x), wai = bfhi(w.x);
      float wbr = bflo(w.y), wbi = bfhi(w.y);
      ar += ner[d]*war - nei[d]*wai;
      ai += ner[d]*wai + nei[d]*war;
      br += ner[d]*wbr - nei[d]*wbi;
      bi += ner[d]*wbi + nei[d]*wbr;
    }
    unsigned short bAr = (unsigned short)f2bf(ar);
    unsigned short bAi = (unsigned short)f2bf(ai);
    unsigned short bBr = (unsigned short)f2bf(br);
    unsigned short bBi = (unsigned short)f2bf(bi);
    unsigned short bNBi = bBi ^ 0x8000u;
    sW[o*WPITCH + iB]            = bAr;
    sW[o*WPITCH + 64 + iB]       = bBr;
    sW[o*WPITCH + 128 + iB]      = bNBi;
    sW[(64+o)*WPITCH + iB]       = bAi;
    sW[(64+o)*WPITCH + 64 + iB]  = bBi;
    sW[(64+o)*WPITCH + 128 + iB] = bBr;
  }

  // ---- phase C: U = [x, yr, yi] -> sU
  const uint32_t* Yp = reinterpret_cast<const uint32_t*>(ws + WS_Y) + (size_t)u * BI;
  #pragma unroll 2
  for (int j = 0; j < 8; ++j) {
    int bi_ = j*512 + t;
    int b = bi_ >> 6, i = bi_ & 63;
    float xv = x[((size_t)b*VV + u)*CI + i];
    uint32_t p = Yp[bi_];
    sU[b*WPITCH + i]       = (unsigned short)f2bf(xv);
    sU[b*WPITCH + 64 + i]  = (unsigned short)(p & 0xFFFFu);
    sU[b*WPITCH + 128 + i] = (unsigned short)(p >> 16);
  }
  __syncthreads();

  // ---- phase D: MFMA. wave w owns N-tile w (o2 = 16w..16w+15), all 4 M-tiles.
  int w = t >> 6, lane = t & 63;
  int n16 = lane & 15, quad = lane >> 4;
  f32x4 acc[4];
  #pragma unroll
  for (int m = 0; m < 4; ++m) acc[m] = (f32x4){0.f, 0.f, 0.f, 0.f};

  #pragma unroll
  for (int ks = 0; ks < 6; ++ks) {
    int kb = ks*32 + quad*8;
    short8 bfrag = *(const short8*)&sW[(w*16 + n16)*WPITCH + kb];
    #pragma unroll
    for (int m = 0; m < 4; ++m) {
      short8 afrag = *(const short8*)&sU[(m*16 + n16)*WPITCH + kb];
      acc[m] = __builtin_amdgcn_mfma_f32_16x16x32_bf16(afrag, bfrag, acc[m], 0, 0, 0);
    }
  }

  // ---- epilogue: bias + store
  int o2 = w*16 + n16;
  int comp = o2 >> 6, o = o2 & 63;
  float bias = 0.f;
  #pragma unroll
  for (int d = 0; d < DD; ++d) {
    float pr = b_re[d*CO + o], pi = b_im[d*CO + o];
    float c1 = comp ? pi : pr;
    float c2 = comp ? pr : -pi;
    bias += ner[d]*c1 + nei[d]*c2;
  }
  #pragma unroll
  for (int m = 0; m < 4; ++m) {
    #pragma unroll
    for (int r = 0; r < 4; ++r) {
      int b = m*16 + quad*4 + r;
      out[((size_t)b*VV + u)*(2*CO) + 2*o + comp] = acc[m][r] + bias;
    }
  }
}

// ---------------------------------------------------------------------------
extern "C" void kernel_launch(void* const* d_in, const int* in_sizes, int n_in,
                              void* d_out, int out_size, void* d_ws, size_t ws_size,
                              hipStream_t stream) {
  (void)in_sizes; (void)n_in; (void)out_size; (void)ws_size;
  const float* x     = (const float*)d_in[0];
  const float* ne_re = (const float*)d_in[1];
  const float* ne_im = (const float*)d_in[2];
  const float* w_re  = (const float*)d_in[3];
  const float* w_im  = (const float*)d_in[4];
  const float* b_re  = (const float*)d_in[5];
  const float* b_im  = (const float*)d_in[6];
  float* out = (float*)d_out;
  float* ws  = (float*)d_ws;

  k_zero <<<dim3(129),      dim3(256),  0, stream>>>(ws);
  k_prep <<<dim3(256),      dim3(256),  0, stream>>>(w_re, w_im, ws);
  k_norm1<<<dim3(8),        dim3(256),  0, stream>>>(ne_re, ne_im, ws);
  k_norm2<<<dim3(1),        dim3(256),  0, stream>>>(ws);
  k_z    <<<dim3(512),      dim3(1024), 0, stream>>>(x, ne_re, ne_im, ws);
  k_y    <<<dim3(500, 16),  dim3(256),  0, stream>>>(ne_re, ne_im, ws);
  k_final<<<dim3(VV),       dim3(512),  0, stream>>>(x, ne_re, ne_im, b_re, b_im, ws, out);
}

// Round 3
// 305.341 us; speedup vs baseline: 1.9210x; 1.1639x over previous
//
#include <hip/hip_runtime.h>
#include <stdint.h>

// Problem constants
#define BB 64
#define VV 2000
#define DD 16
#define CI 64
#define CO 64

// ---- ws layout ----
// dword offsets (fp32 region)
#define WS_INV_DW   0
#define WS_GRAM_DW  8
#define WS_Z_DW     1024                    // float2[16][4096]
#define WS_BIAS_DW  132096                  // fp32 [2000][128]
// byte offsets (bf16 regions), all 16B-aligned
#define WS_NE_B     1552384UL               // bf16 [2048][64]  (hi/lo split ne)
#define WS_RHS_B    1814528UL               // bf16 [24576][64] (RHS_T, swizzle baked)
#define WS_U_B      4960256UL               // bf16 [2000][64*192]
#define WS_W_B      54112256UL              // bf16 [2000][128*192]
// total ~152.4 MB

#define NROW 192        // K per node-row (3 comps x 64)
#define NPN  24576      // 128*192 elems per node (W)
#define UPN  12288      // 64*192 elems per node (U)

typedef __attribute__((ext_vector_type(8))) short short8;
typedef __attribute__((ext_vector_type(4))) float f32x4;

__device__ __forceinline__ uint32_t f2bf(float f) {
  uint32_t u = __float_as_uint(f);
  return (u + 0x7FFFu + ((u >> 16) & 1u)) >> 16;   // RNE
}
// granule swizzle: row r, logical granule g in [0,24) -> physical granule
__device__ __forceinline__ int swz(int g, int r) { return (g & 24) | ((g ^ r) & 7); }

// ---------------------------------------------------------------------------
// K0: zero INV+GRAM+Z region: dwords [0, 132096) = 129 blocks * 256 * 4
__global__ void k_zero(float* __restrict__ ws) {
  int idx4 = blockIdx.x * 256 + threadIdx.x;
  reinterpret_cast<float4*>(ws)[idx4] = make_float4(0.f, 0.f, 0.f, 0.f);
}

// K1: NE[u][col] bf16, col = h*32 + d*2 + p; h=0: bf16(ne), h=1: bf16(ne - hi)
__global__ void k_ne(const float* __restrict__ ne_re, const float* __restrict__ ne_im,
                     float* __restrict__ ws) {
  int gid = blockIdx.x * 256 + threadIdx.x;   // 512 blocks -> 131072
  int u = gid >> 6, col = gid & 63;
  int h = col >> 5, kk = col & 31, d = kk >> 1, p = kk & 1;
  float v = 0.f;
  if (u < VV) v = p ? ne_im[u*DD + d] : ne_re[u*DD + d];
  uint32_t hi = f2bf(v);
  uint32_t ov = h ? f2bf(v - __uint_as_float(hi << 16)) : hi;
  ((uint16_t*)((char*)ws + WS_NE_B))[gid] = (uint16_t)ov;
}

// K2: RHS_T[n][k] bf16; n = physical (o2*192 + swizzled pos); k = h*32 + d*2 + p
__global__ void k_rhs(const float* __restrict__ w_re, const float* __restrict__ w_im,
                      float* __restrict__ ws) {
  int t = threadIdx.x;
  int n = blockIdx.x * 4 + (t >> 6);          // 6144 blocks -> 24576 rows
  int k = t & 63;
  int o2 = n / NROW;
  int pph = n - o2 * NROW;                    // 0..191 physical pos
  int gp = pph >> 3, e = pph & 7;
  int g  = (gp & 24) | ((gp ^ o2) & 7);       // un-swizzle (XOR self-inverse)
  int cb = g >> 3, i = ((g & 7) << 3) | e;
  int half = o2 >> 6, o = o2 & 63;
  int kk = k & 31, d = kk >> 1, p = kk & 1;
  // comp: 0=Ar 1=Ai 2=Br 3=Bi ; wA=w0-w2, wB=w1+2w2
  int comp; float sgn;
  if (half == 0) {
    if      (cb == 0) { comp = p ? 1 : 0; sgn = p ? -1.f : 1.f; }
    else if (cb == 1) { comp = p ? 3 : 2; sgn = p ? -1.f : 1.f; }
    else              { comp = p ? 2 : 3; sgn = -1.f; }
  } else {
    if      (cb == 0) { comp = p ? 0 : 1; sgn = 1.f; }
    else if (cb == 1) { comp = p ? 2 : 3; sgn = 1.f; }
    else              { comp = p ? 3 : 2; sgn = p ? -1.f : 1.f; }
  }
  const float* pool = (comp == 0 || comp == 2) ? w_re : w_im;
  int b0 = ((d*3 + 0)*64 + i)*64 + o;         // w[d,kc,i,o], kc stride 4096
  float val = (comp < 2) ? (pool[b0] - pool[b0 + 8192])
                         : (pool[b0 + 4096] + 2.f*pool[b0 + 8192]);
  ((uint16_t*)((char*)ws + WS_RHS_B))[n*64 + k] = (uint16_t)f2bf(sgn * val);
}

// K3a: partial Gram, 25 blocks x 80 v
__global__ void k_norm1(const float* __restrict__ ne_re, const float* __restrict__ ne_im,
                        float* __restrict__ ws) {
  int t = threadIdx.x;
  int d = t >> 4, e = t & 15;
  int v0 = blockIdx.x * 80;
  float gr = 0.f, gi = 0.f;
  for (int v = v0; v < v0 + 80; ++v) {
    float ar = ne_re[v*DD + d], ai = ne_im[v*DD + d];
    float br = ne_re[v*DD + e], bi = ne_im[v*DD + e];
    gr += ar*br + ai*bi;
    gi += ar*bi - ai*br;
  }
  atomicAdd(ws + WS_GRAM_DW + 2*t,     gr);
  atomicAdd(ws + WS_GRAM_DW + 2*t + 1, gi);
}

// K3b: inv_norm
__global__ void k_norm2(float* __restrict__ ws) {
  int t = threadIdx.x;
  float gr = ws[WS_GRAM_DW + 2*t], gi = ws[WS_GRAM_DW + 2*t + 1];
  __shared__ float red[256];
  red[t] = gr*gr + gi*gi;
  __syncthreads();
  for (int k = 128; k > 0; k >>= 1) {
    if (t < k) red[t] += red[t + k];
    __syncthreads();
  }
  if (t == 0) ws[WS_INV_DW] = 1.0f / sqrtf(red[0]);
}

// K4: bias2[u][o2] fp32
__global__ void k_bias(const float* __restrict__ ne_re, const float* __restrict__ ne_im,
                       const float* __restrict__ b_re, const float* __restrict__ b_im,
                       float* __restrict__ ws) {
  int gid = blockIdx.x * 256 + threadIdx.x;   // 1000 blocks -> 256000
  int u = gid >> 7, o2 = gid & 127;
  int half = o2 >> 6, o = o2 & 63;
  float acc = 0.f;
  #pragma unroll
  for (int d = 0; d < DD; ++d) {
    float nr = ne_re[u*DD + d], ni = ne_im[u*DD + d];
    float pr = b_re[d*CO + o],  pi = b_im[d*CO + o];
    acc += half ? (nr*pi + ni*pr) : (nr*pr - ni*pi);
  }
  ws[WS_BIAS_DW + gid] = acc;
}

// K5: Z[d][bi] += sum_v conj(ne[v,d]) * x[b,v,i]; d held in registers, x read once
// grid 512 = (b:64) x (chunk:8), block 64 (1 wave, lanes = i)
__global__ void k_z(const float* __restrict__ x, const float* __restrict__ ne_re,
                    const float* __restrict__ ne_im, float* __restrict__ ws) {
  int b = blockIdx.x >> 3, c = blockIdx.x & 7;
  int i = threadIdx.x;
  const float* xp = x + (size_t)(b*VV + c*250)*CI + i;
  float zr[DD], zi[DD];
  #pragma unroll
  for (int d = 0; d < DD; ++d) { zr[d] = 0.f; zi[d] = 0.f; }
  int v0 = c * 250;
  for (int v = v0; v < v0 + 250; ++v) {
    float xv = *xp; xp += CI;
    #pragma unroll
    for (int d = 0; d < DD; ++d) {
      float nr = ne_re[v*DD + d], ni = ne_im[v*DD + d];   // wave-uniform s_loads
      zr[d] += nr * xv;
      zi[d] -= ni * xv;
    }
  }
  float* Z = ws + WS_Z_DW;
  #pragma unroll
  for (int d = 0; d < DD; ++d) {
    float* zp = Z + (size_t)(d*4096 + b*64 + i) * 2;
    atomicAdd(zp,     zr[d]);
    atomicAdd(zp + 1, zi[d]);
  }
}

// K6: W GEMM: C[u][n] = sum_k NE[u,k] * RHS_T[n,k], bf16 out, MFMA 16x16x32
// grid (32 ut, 24 nc), block 256 (4 waves); wave: 64 u-rows x 256 n
__global__ void __launch_bounds__(256, 4)
k_wgemm(float* __restrict__ ws) {
  const uint16_t* NE  = (const uint16_t*)((char*)ws + WS_NE_B);
  const uint16_t* RHS = (const uint16_t*)((char*)ws + WS_RHS_B);
  uint16_t*       W   = (uint16_t*)((char*)ws + WS_W_B);
  int ut = blockIdx.x, nc = blockIdx.y;
  int t = threadIdx.x, w = t >> 6, lane = t & 63;
  int n16 = lane & 15, quad = lane >> 4;
  short8 a[4][2];
  #pragma unroll
  for (int m = 0; m < 4; ++m) {
    int u = ut*64 + m*16 + n16;
    a[m][0] = *(const short8*)(NE + u*64 + quad*8);
    a[m][1] = *(const short8*)(NE + u*64 + 32 + quad*8);
  }
  int nb = nc*1024 + w*256;
  for (int nt = 0; nt < 16; ++nt) {
    int n = nb + nt*16 + n16;
    short8 b0 = *(const short8*)(RHS + (size_t)n*64 + quad*8);
    short8 b1 = *(const short8*)(RHS + (size_t)n*64 + 32 + quad*8);
    #pragma unroll
    for (int m = 0; m < 4; ++m) {
      f32x4 acc = (f32x4){0.f, 0.f, 0.f, 0.f};
      acc = __builtin_amdgcn_mfma_f32_16x16x32_bf16(a[m][0], b0, acc, 0, 0, 0);
      acc = __builtin_amdgcn_mfma_f32_16x16x32_bf16(a[m][1], b1, acc, 0, 0, 0);
      #pragma unroll
      for (int r = 0; r < 4; ++r) {
        int u = ut*64 + m*16 + quad*4 + r;
        if (u < VV) W[(size_t)u*NPN + n] = (uint16_t)f2bf(acc[r]);
      }
    }
  }
}

// K7: U[u] rows: [x | yr | yi] bf16, swizzled; Z columns held in registers over 16 u
// grid (125 ug, 16 by), block 256 = 4 b x 64 i
__global__ void __launch_bounds__(256, 4)
k_u(const float* __restrict__ x, const float* __restrict__ ne_re,
    const float* __restrict__ ne_im, float* __restrict__ ws) {
  int ug = blockIdx.x, by = blockIdx.y;
  int t = threadIdx.x, q = t >> 6, lane = t & 63;
  int b = by*4 + q;
  float invn = ws[WS_INV_DW];
  const float* Z = ws + WS_Z_DW;
  float zr[DD], zi[DD];
  #pragma unroll
  for (int d = 0; d < DD; ++d) {
    const float* zp = Z + (size_t)(d*4096 + b*64 + lane) * 2;
    zr[d] = zp[0]; zi[d] = zp[1];
  }
  uint16_t* U = (uint16_t*)((char*)ws + WS_U_B);
  int i = lane;
  int p0 = swz(0*8 + (i >> 3), b)*8 + (i & 7);
  int p1 = swz(1*8 + (i >> 3), b)*8 + (i & 7);
  int p2 = swz(2*8 + (i >> 3), b)*8 + (i & 7);
  for (int ul = 0; ul < 16; ++ul) {
    int u = ug*16 + ul;
    float yr = 0.f, yi = 0.f;
    #pragma unroll
    for (int d = 0; d < DD; ++d) {
      float nr = ne_re[u*DD + d], ni = ne_im[u*DD + d];
      yr += nr*zr[d] - ni*zi[d];
      yi += nr*zi[d] + ni*zr[d];
    }
    float xv = x[((size_t)b*VV + u)*CI + i];
    uint16_t* Urow = U + (size_t)u*UPN + b*NROW;
    Urow[p0] = (uint16_t)f2bf(xv);
    Urow[p1] = (uint16_t)f2bf(yr * invn);
    Urow[p2] = (uint16_t)f2bf(yi * invn);
  }
}

// K8: per-node streaming MFMA: copy W,U -> LDS, 24 MFMA, bias, store
__global__ void __launch_bounds__(512, 4)
k_final(const float* __restrict__ ws, float* __restrict__ out) {
  int u = blockIdx.x, t = threadIdx.x;
  __shared__ __align__(16) uint16_t sW[128 * NROW];
  __shared__ __align__(16) uint16_t sU[64 * NROW];
  const uint4* Wg = (const uint4*)((const char*)ws + WS_W_B + (size_t)u*NPN*2);
  const uint4* Ug = (const uint4*)((const char*)ws + WS_U_B + (size_t)u*UPN*2);
  uint4* sWv = (uint4*)sW;
  uint4* sUv = (uint4*)sU;
  #pragma unroll
  for (int j = 0; j < 6; ++j) sWv[j*512 + t] = Wg[j*512 + t];
  #pragma unroll
  for (int j = 0; j < 3; ++j) sUv[j*512 + t] = Ug[j*512 + t];
  __syncthreads();

  int w = t >> 6, lane = t & 63;
  int n16 = lane & 15, quad = lane >> 4;
  int ro = w*16 + n16;                        // o2 row
  f32x4 acc[4];
  #pragma unroll
  for (int m = 0; m < 4; ++m) acc[m] = (f32x4){0.f, 0.f, 0.f, 0.f};

  #pragma unroll
  for (int ks = 0; ks < 6; ++ks) {
    int gg = ks*4 + quad;
    short8 bfrag = *(const short8*)&sW[ro*NROW + swz(gg, ro)*8];
    #pragma unroll
    for (int m = 0; m < 4; ++m) {
      int rb = m*16 + n16;
      short8 afrag = *(const short8*)&sU[rb*NROW + swz(gg, rb)*8];
      acc[m] = __builtin_amdgcn_mfma_f32_16x16x32_bf16(afrag, bfrag, acc[m], 0, 0, 0);
    }
  }

  float bias = ws[WS_BIAS_DW + u*128 + ro];
  int comp = ro >> 6, o = ro & 63;
  #pragma unroll
  for (int m = 0; m < 4; ++m) {
    #pragma unroll
    for (int r = 0; r < 4; ++r) {
      int b = m*16 + quad*4 + r;
      out[((size_t)b*VV + u)*(2*CO) + 2*o + comp] = acc[m][r] + bias;
    }
  }
}

// ---------------------------------------------------------------------------
extern "C" void kernel_launch(void* const* d_in, const int* in_sizes, int n_in,
                              void* d_out, int out_size, void* d_ws, size_t ws_size,
                              hipStream_t stream) {
  (void)in_sizes; (void)n_in; (void)out_size; (void)ws_size;
  const float* x     = (const float*)d_in[0];
  const float* ne_re = (const float*)d_in[1];
  const float* ne_im = (const float*)d_in[2];
  const float* w_re  = (const float*)d_in[3];
  const float* w_im  = (const float*)d_in[4];
  const float* b_re  = (const float*)d_in[5];
  const float* b_im  = (const float*)d_in[6];
  float* out = (float*)d_out;
  float* ws  = (float*)d_ws;

  k_zero <<<dim3(129),        dim3(256), 0, stream>>>(ws);
  k_ne   <<<dim3(512),        dim3(256), 0, stream>>>(ne_re, ne_im, ws);
  k_rhs  <<<dim3(6144),       dim3(256), 0, stream>>>(w_re, w_im, ws);
  k_norm1<<<dim3(25),         dim3(256), 0, stream>>>(ne_re, ne_im, ws);
  k_norm2<<<dim3(1),          dim3(256), 0, stream>>>(ws);
  k_bias <<<dim3(1000),       dim3(256), 0, stream>>>(ne_re, ne_im, b_re, b_im, ws);
  k_z    <<<dim3(512),        dim3(64),  0, stream>>>(x, ne_re, ne_im, ws);
  k_wgemm<<<dim3(32, 24),     dim3(256), 0, stream>>>(ws);
  k_u    <<<dim3(125, 16),    dim3(256), 0, stream>>>(x, ne_re, ne_im, ws);
  k_final<<<dim3(VV),         dim3(512), 0, stream>>>(ws, out);
}

// Round 4
// 290.058 us; speedup vs baseline: 2.0223x; 1.0527x over previous
//
#include <hip/hip_runtime.h>
#include <stdint.h>

// Problem constants
#define BB 64
#define VV 2000
#define DD 16
#define CI 64
#define CO 64

// ---- ws layout ----
// dword offsets (fp32 region)
#define WS_INV_DW   0
#define WS_GRAM_DW  8
#define WS_Z_DW     1024                    // float2[16][4096]
#define WS_BIAS_DW  132096                  // fp32 [2000][128]
// byte offsets (bf16 regions), all 16B-aligned
#define WS_NE_B     1552384UL               // bf16 [2048][64]  (hi/lo split ne)
#define WS_RHS_B    1814528UL               // bf16 [24576][64] (RHS_T, swizzle baked)
#define WS_U_B      4960256UL               // bf16 [2000][64*192]
#define WS_W_B      54112256UL              // bf16 [2000][128*192]
// ZP (k_z partials) aliases the W region: fully consumed by k_zred BEFORE
// k_wgemm writes W.  fp32 [16][16][4096][2] = 8 MB
#define WS_ZP_DW    (WS_W_B / 4)
// total ~152.4 MB

#define NROW 192        // K per node-row (3 comps x 64)
#define NPN  24576      // 128*192 elems per node (W)
#define UPN  12288      // 64*192 elems per node (U)

typedef __attribute__((ext_vector_type(8))) short short8;
typedef __attribute__((ext_vector_type(4))) float f32x4;

__device__ __forceinline__ uint32_t f2bf(float f) {
  uint32_t u = __float_as_uint(f);
  return (u + 0x7FFFu + ((u >> 16) & 1u)) >> 16;   // RNE
}
// granule swizzle: row r, logical granule g in [0,24) -> physical granule
__device__ __forceinline__ int swz(int g, int r) { return (g & 24) | ((g ^ r) & 7); }

// ---------------------------------------------------------------------------
// K0: zero INV+GRAM (dwords [0,1024))
__global__ void k_zero(float* __restrict__ ws) {
  reinterpret_cast<float4*>(ws)[threadIdx.x] = make_float4(0.f, 0.f, 0.f, 0.f);
}

// K1: NE[u][col] bf16, col = h*32 + d*2 + p; h=0: bf16(ne), h=1: bf16(ne - hi)
__global__ void k_ne(const float* __restrict__ ne_re, const float* __restrict__ ne_im,
                     float* __restrict__ ws) {
  int gid = blockIdx.x * 256 + threadIdx.x;   // 512 blocks -> 131072
  int u = gid >> 6, col = gid & 63;
  int h = col >> 5, kk = col & 31, d = kk >> 1, p = kk & 1;
  float v = 0.f;
  if (u < VV) v = p ? ne_im[u*DD + d] : ne_re[u*DD + d];
  uint32_t hi = f2bf(v);
  uint32_t ov = h ? f2bf(v - __uint_as_float(hi << 16)) : hi;
  ((uint16_t*)((char*)ws + WS_NE_B))[gid] = (uint16_t)ov;
}

// K2: RHS_T[n][k] bf16 — coalesced rewrite. Block = (half, cb, igroup);
// 256 threads = 4 i x 64 o (lanes on o => pool reads are 256B coalesced).
// Each thread emits one full 64-k row (128B contiguous store).
__global__ void k_rhs(const float* __restrict__ w_re, const float* __restrict__ w_im,
                      float* __restrict__ ws) {
  int bx = blockIdx.x;                 // 96 = 2 half * 3 cb * 16 ig
  int ig = bx & 15, cb = (bx >> 4) % 3, half = bx / 48;
  int t = threadIdx.x;
  int o = t & 63, il = t >> 6;
  int i = ig*4 + il;
  int o2 = half*64 + o;
  int gp  = cb*8 + (i >> 3);
  int gph = (gp & 24) | ((gp ^ o2) & 7);
  int pos = gph*8 + (i & 7);
  int n = o2*NROW + pos;

  uint32_t row32[16];
  #pragma unroll
  for (int d = 0; d < DD; ++d) {
    int b0 = (d*192 + i)*64 + o;       // w[d,kc,i,o]: d stride 12288, kc 4096
    float vre, vim;
    if (cb == 0) {                     // wA = w0 - w2
      vre = w_re[b0] - w_re[b0 + 8192];
      vim = w_im[b0] - w_im[b0 + 8192];
    } else {                           // wB = w1 + 2*w2
      vre = w_re[b0 + 4096] + 2.f*w_re[b0 + 8192];
      vim = w_im[b0 + 4096] + 2.f*w_im[b0 + 8192];
    }
    float q0, q1;
    if (half == 0) {
      if (cb <= 1) { q0 = vre;  q1 = -vim; }   // Ar,-Ai | Br,-Bi
      else         { q0 = -vim; q1 = -vre; }   // -Bi,-Br
    } else {
      if (cb <= 1) { q0 = vim;  q1 = vre;  }   // Ai,Ar | Bi,Br
      else         { q0 = vre;  q1 = -vim; }   // Br,-Bi
    }
    row32[d] = f2bf(q0) | (f2bf(q1) << 16);
  }
  uint4* dst = (uint4*)((uint16_t*)((char*)ws + WS_RHS_B) + (size_t)n*64);
  #pragma unroll
  for (int j = 0; j < 4; ++j) {
    uint4 qv = make_uint4(row32[4*j], row32[4*j+1], row32[4*j+2], row32[4*j+3]);
    dst[j]     = qv;   // h=0 half
    dst[j + 4] = qv;   // h=1 duplicate
  }
}

// K3a: partial Gram, 25 blocks x 80 v
__global__ void k_norm1(const float* __restrict__ ne_re, const float* __restrict__ ne_im,
                        float* __restrict__ ws) {
  int t = threadIdx.x;
  int d = t >> 4, e = t & 15;
  int v0 = blockIdx.x * 80;
  float gr = 0.f, gi = 0.f;
  for (int v = v0; v < v0 + 80; ++v) {
    float ar = ne_re[v*DD + d], ai = ne_im[v*DD + d];
    float br = ne_re[v*DD + e], bi = ne_im[v*DD + e];
    gr += ar*br + ai*bi;
    gi += ar*bi - ai*br;
  }
  atomicAdd(ws + WS_GRAM_DW + 2*t,     gr);
  atomicAdd(ws + WS_GRAM_DW + 2*t + 1, gi);
}

// K3b: inv_norm
__global__ void k_norm2(float* __restrict__ ws) {
  int t = threadIdx.x;
  float gr = ws[WS_GRAM_DW + 2*t], gi = ws[WS_GRAM_DW + 2*t + 1];
  __shared__ float red[256];
  red[t] = gr*gr + gi*gi;
  __syncthreads();
  for (int k = 128; k > 0; k >>= 1) {
    if (t < k) red[t] += red[t + k];
    __syncthreads();
  }
  if (t == 0) ws[WS_INV_DW] = 1.0f / sqrtf(red[0]);
}

// K4: bias2[u][o2] fp32
__global__ void k_bias(const float* __restrict__ ne_re, const float* __restrict__ ne_im,
                       const float* __restrict__ b_re, const float* __restrict__ b_im,
                       float* __restrict__ ws) {
  int gid = blockIdx.x * 256 + threadIdx.x;   // 1000 blocks -> 256000
  int u = gid >> 7, o2 = gid & 127;
  int half = o2 >> 6, o = o2 & 63;
  float acc = 0.f;
  #pragma unroll
  for (int d = 0; d < DD; ++d) {
    float nr = ne_re[u*DD + d], ni = ne_im[u*DD + d];
    float pr = b_re[d*CO + o],  pi = b_im[d*CO + o];
    acc += half ? (nr*pi + ni*pr) : (nr*pr - ni*pi);
  }
  ws[WS_BIAS_DW + gid] = acc;
}

// K5: Z partials. grid 1024 = (b:64)x(chunk:16), block 256 = 4 waves x 64 lanes.
// Wave w covers ~31 v of the 125-v chunk; lanes = i. No atomics: per-chunk
// partials ZP[c][d][b*64+i][p], cross-wave reduced through LDS.
__global__ void __launch_bounds__(256, 4)
k_z(const float* __restrict__ x, const float* __restrict__ ne_re,
    const float* __restrict__ ne_im, float* __restrict__ ws) {
  int b = blockIdx.x >> 4, c = blockIdx.x & 15;
  int t = threadIdx.x, w = t >> 6, i = t & 63;
  __shared__ float sred[4 * 2048];

  float zr[DD], zi[DD];
  #pragma unroll
  for (int d = 0; d < DD; ++d) { zr[d] = 0.f; zi[d] = 0.f; }

  int vbase = c * 125;
  int v0 = vbase + ((w * 125) >> 2);
  int v1 = vbase + (((w + 1) * 125) >> 2);
  const float* xp = x + ((size_t)b * VV + v0) * CI + i;
  #pragma unroll 4
  for (int v = v0; v < v1; ++v) {
    float xv = *xp; xp += CI;
    #pragma unroll
    for (int d = 0; d < DD; ++d) {
      zr[d] += ne_re[v*DD + d] * xv;    // wave-uniform s_loads
      zi[d] -= ne_im[v*DD + d] * xv;
    }
  }
  #pragma unroll
  for (int d = 0; d < DD; ++d) {
    sred[w*2048 + d*128 + i*2 + 0] = zr[d];   // 2-way alias: free
    sred[w*2048 + d*128 + i*2 + 1] = zi[d];
  }
  __syncthreads();
  float* ZP = ws + WS_ZP_DW;
  #pragma unroll
  for (int k = 0; k < 8; ++k) {
    int j = t + k*256;                        // 0..2047 = d*128 + r
    float s = sred[j] + sred[2048 + j] + sred[4096 + j] + sred[6144 + j];
    int d = j >> 7, r = j & 127;
    ZP[(size_t)c*131072 + d*8192 + b*128 + r] = s;
  }
}

// K5b: Z = sum over 16 chunks of ZP
__global__ void k_zred(float* __restrict__ ws) {
  int g = blockIdx.x * 256 + threadIdx.x;     // 256 blocks -> 65536 float2
  const float2* ZP2 = (const float2*)(ws + WS_ZP_DW);
  float2 acc = make_float2(0.f, 0.f);
  #pragma unroll
  for (int c = 0; c < 16; ++c) {
    float2 v = ZP2[(size_t)c*65536 + g];
    acc.x += v.x; acc.y += v.y;
  }
  ((float2*)(ws + WS_Z_DW))[g] = acc;
}

// K6: W GEMM: C[u][n] = sum_k NE[u,k] * RHS_T[n,k], bf16 out, MFMA 16x16x32
__global__ void __launch_bounds__(256, 4)
k_wgemm(float* __restrict__ ws) {
  const uint16_t* NE  = (const uint16_t*)((char*)ws + WS_NE_B);
  const uint16_t* RHS = (const uint16_t*)((char*)ws + WS_RHS_B);
  uint16_t*       W   = (uint16_t*)((char*)ws + WS_W_B);
  int ut = blockIdx.x, nc = blockIdx.y;
  int t = threadIdx.x, w = t >> 6, lane = t & 63;
  int n16 = lane & 15, quad = lane >> 4;
  short8 a[4][2];
  #pragma unroll
  for (int m = 0; m < 4; ++m) {
    int u = ut*64 + m*16 + n16;
    a[m][0] = *(const short8*)(NE + u*64 + quad*8);
    a[m][1] = *(const short8*)(NE + u*64 + 32 + quad*8);
  }
  int nb = nc*1024 + w*256;
  for (int nt = 0; nt < 16; ++nt) {
    int n = nb + nt*16 + n16;
    short8 b0 = *(const short8*)(RHS + (size_t)n*64 + quad*8);
    short8 b1 = *(const short8*)(RHS + (size_t)n*64 + 32 + quad*8);
    #pragma unroll
    for (int m = 0; m < 4; ++m) {
      f32x4 acc = (f32x4){0.f, 0.f, 0.f, 0.f};
      acc = __builtin_amdgcn_mfma_f32_16x16x32_bf16(a[m][0], b0, acc, 0, 0, 0);
      acc = __builtin_amdgcn_mfma_f32_16x16x32_bf16(a[m][1], b1, acc, 0, 0, 0);
      #pragma unroll
      for (int r = 0; r < 4; ++r) {
        int u = ut*64 + m*16 + quad*4 + r;
        if (u < VV) W[(size_t)u*NPN + n] = (uint16_t)f2bf(acc[r]);
      }
    }
  }
}

// K7: U[u] rows: [x | yr | yi] bf16, swizzled; Z columns in registers over 16 u
__global__ void __launch_bounds__(256, 4)
k_u(const float* __restrict__ x, const float* __restrict__ ne_re,
    const float* __restrict__ ne_im, float* __restrict__ ws) {
  int ug = blockIdx.x, by = blockIdx.y;
  int t = threadIdx.x, q = t >> 6, lane = t & 63;
  int b = by*4 + q;
  float invn = ws[WS_INV_DW];
  const float* Z = ws + WS_Z_DW;
  float zr[DD], zi[DD];
  #pragma unroll
  for (int d = 0; d < DD; ++d) {
    const float* zp = Z + (size_t)(d*4096 + b*64 + lane) * 2;
    zr[d] = zp[0]; zi[d] = zp[1];
  }
  uint16_t* U = (uint16_t*)((char*)ws + WS_U_B);
  int i = lane;
  int p0 = swz(0*8 + (i >> 3), b)*8 + (i & 7);
  int p1 = swz(1*8 + (i >> 3), b)*8 + (i & 7);
  int p2 = swz(2*8 + (i >> 3), b)*8 + (i & 7);
  for (int ul = 0; ul < 16; ++ul) {
    int u = ug*16 + ul;
    float yr = 0.f, yi = 0.f;
    #pragma unroll
    for (int d = 0; d < DD; ++d) {
      float nr = ne_re[u*DD + d], ni = ne_im[u*DD + d];
      yr += nr*zr[d] - ni*zi[d];
      yi += nr*zi[d] + ni*zr[d];
    }
    float xv = x[((size_t)b*VV + u)*CI + i];
    uint16_t* Urow = U + (size_t)u*UPN + b*NROW;
    Urow[p0] = (uint16_t)f2bf(xv);
    Urow[p1] = (uint16_t)f2bf(yr * invn);
    Urow[p2] = (uint16_t)f2bf(yi * invn);
  }
}

// K8: per-node streaming MFMA: copy W,U -> LDS, 24 MFMA, bias, store
__global__ void __launch_bounds__(512, 2)
k_final(const float* __restrict__ ws, float* __restrict__ out) {
  int u = blockIdx.x, t = threadIdx.x;
  __shared__ __align__(16) uint16_t sW[128 * NROW];
  __shared__ __align__(16) uint16_t sU[64 * NROW];
  const uint4* Wg = (const uint4*)((const char*)ws + WS_W_B + (size_t)u*NPN*2);
  const uint4* Ug = (const uint4*)((const char*)ws + WS_U_B + (size_t)u*UPN*2);
  uint4* sWv = (uint4*)sW;
  uint4* sUv = (uint4*)sU;
  #pragma unroll
  for (int j = 0; j < 6; ++j) sWv[j*512 + t] = Wg[j*512 + t];
  #pragma unroll
  for (int j = 0; j < 3; ++j) sUv[j*512 + t] = Ug[j*512 + t];
  __syncthreads();

  int w = t >> 6, lane = t & 63;
  int n16 = lane & 15, quad = lane >> 4;
  int ro = w*16 + n16;                        // o2 row
  f32x4 acc[4];
  #pragma unroll
  for (int m = 0; m < 4; ++m) acc[m] = (f32x4){0.f, 0.f, 0.f, 0.f};

  #pragma unroll
  for (int ks = 0; ks < 6; ++ks) {
    int gg = ks*4 + quad;
    short8 bfrag = *(const short8*)&sW[ro*NROW + swz(gg, ro)*8];
    #pragma unroll
    for (int m = 0; m < 4; ++m) {
      int rb = m*16 + n16;
      short8 afrag = *(const short8*)&sU[rb*NROW + swz(gg, rb)*8];
      acc[m] = __builtin_amdgcn_mfma_f32_16x16x32_bf16(afrag, bfrag, acc[m], 0, 0, 0);
    }
  }

  float bias = ws[WS_BIAS_DW + u*128 + ro];
  int comp = ro >> 6, o = ro & 63;
  #pragma unroll
  for (int m = 0; m < 4; ++m) {
    #pragma unroll
    for (int r = 0; r < 4; ++r) {
      int b = m*16 + quad*4 + r;
      out[((size_t)b*VV + u)*(2*CO) + 2*o + comp] = acc[m][r] + bias;
    }
  }
}

// ---------------------------------------------------------------------------
extern "C" void kernel_launch(void* const* d_in, const int* in_sizes, int n_in,
                              void* d_out, int out_size, void* d_ws, size_t ws_size,
                              hipStream_t stream) {
  (void)in_sizes; (void)n_in; (void)out_size; (void)ws_size;
  const float* x     = (const float*)d_in[0];
  const float* ne_re = (const float*)d_in[1];
  const float* ne_im = (const float*)d_in[2];
  const float* w_re  = (const float*)d_in[3];
  const float* w_im  = (const float*)d_in[4];
  const float* b_re  = (const float*)d_in[5];
  const float* b_im  = (const float*)d_in[6];
  float* out = (float*)d_out;
  float* ws  = (float*)d_ws;

  k_zero <<<dim3(1),          dim3(256), 0, stream>>>(ws);
  k_ne   <<<dim3(512),        dim3(256), 0, stream>>>(ne_re, ne_im, ws);
  k_rhs  <<<dim3(96),         dim3(256), 0, stream>>>(w_re, w_im, ws);
  k_norm1<<<dim3(25),         dim3(256), 0, stream>>>(ne_re, ne_im, ws);
  k_norm2<<<dim3(1),          dim3(256), 0, stream>>>(ws);
  k_bias <<<dim3(1000),       dim3(256), 0, stream>>>(ne_re, ne_im, b_re, b_im, ws);
  k_z    <<<dim3(1024),       dim3(256), 0, stream>>>(x, ne_re, ne_im, ws);
  k_zred <<<dim3(256),        dim3(256), 0, stream>>>(ws);
  k_wgemm<<<dim3(32, 24),     dim3(256), 0, stream>>>(ws);
  k_u    <<<dim3(125, 16),    dim3(256), 0, stream>>>(x, ne_re, ne_im, ws);
  k_final<<<dim3(VV),         dim3(512), 0, stream>>>(ws, out);
}

// Round 5
// 242.694 us; speedup vs baseline: 2.4169x; 1.1952x over previous
//
#include <hip/hip_runtime.h>
#include <stdint.h>

// Problem constants
#define BB 64
#define VV 2000
#define DD 16
#define CI 64
#define CO 64

// ---- ws layout ----
// dword offsets (fp32 region)
#define WS_INV_DW   0
#define WS_GRAM_DW  8
#define WS_Z_DW     1024                    // float2[16][4096]
#define WS_BIAS_DW  132096                  // fp32 [2000][128]  (idx = 2*o+half)
// byte offsets (bf16 regions), all 16B-aligned
#define WS_NE_B     1552384UL               // bf16 [2048][64]  (hi/lo split ne)
#define WS_RHS_B    1814528UL               // bf16 [16384][64] compact RHS
#define WS_U_B      4960256UL               // bf16 [2000][3][64][64] compact U
#define WS_W_B      54112256UL              // bf16 [2000][4][64][64] compact W
// ZP (k_z partials) aliases the W region: consumed by k_zred BEFORE k_wgemm.
#define WS_ZP_DW    (WS_W_B / 4)

typedef __attribute__((ext_vector_type(8))) short short8;
typedef __attribute__((ext_vector_type(4))) float f32x4;

__device__ __forceinline__ uint32_t f2bf(float f) {
  uint32_t u = __float_as_uint(f);
  return (u + 0x7FFFu + ((u >> 16) & 1u)) >> 16;   // RNE
}

// ---------------------------------------------------------------------------
// K0: zero INV+GRAM (dwords [0,1024))
__global__ void k_zero(float* __restrict__ ws) {
  reinterpret_cast<float4*>(ws)[threadIdx.x] = make_float4(0.f, 0.f, 0.f, 0.f);
}

// K1: NE[u][col] bf16, col = h*32 + d*2 + p; h=0: bf16(ne), h=1: bf16(ne - hi)
__global__ void k_ne(const float* __restrict__ ne_re, const float* __restrict__ ne_im,
                     float* __restrict__ ws) {
  int gid = blockIdx.x * 256 + threadIdx.x;   // 512 blocks -> 131072
  int u = gid >> 6, col = gid & 63;
  int h = col >> 5, kk = col & 31, d = kk >> 1, p = kk & 1;
  float v = 0.f;
  if (u < VV) v = p ? ne_im[u*DD + d] : ne_re[u*DD + d];
  uint32_t hi = f2bf(v);
  uint32_t ov = h ? f2bf(v - __uint_as_float(hi << 16)) : hi;
  ((uint16_t*)((char*)ws + WS_NE_B))[gid] = (uint16_t)ov;
}

// K2: compact RHS[n'][k], n' = c*4096 + o*64 + s*8 + e (granule-swizzle baked:
// s = (ig ^ (o&7))&7). Components c: 0=Ar-maker, 1=Ai, 2=Br, 3=Bi.
// cols k = h*32 + d*2 + p: p0 multiplies nr, p1 multiplies ni.
__global__ void k_rhs(const float* __restrict__ w_re, const float* __restrict__ w_im,
                      float* __restrict__ ws) {
  int bx = blockIdx.x;                 // 64 = 4 c * 16 ig4
  int c = bx >> 4, ig4 = bx & 15;
  int t = threadIdx.x;
  int o = t & 63, il = t >> 6;
  int i = ig4*4 + il;
  int cb = c >> 1;                     // 0: wA = w0-w2, 1: wB = w1+2w2
  int imf = c & 1;                     // odd comp: (Im, Re); even: (Re, -Im)

  uint32_t row32[16];
  #pragma unroll
  for (int d = 0; d < DD; ++d) {
    int b0 = (d*192 + i)*64 + o;       // w[d,kc,i,o]: d stride 12288, kc 4096
    float vre, vim;
    if (cb == 0) {
      vre = w_re[b0] - w_re[b0 + 8192];
      vim = w_im[b0] - w_im[b0 + 8192];
    } else {
      vre = w_re[b0 + 4096] + 2.f*w_re[b0 + 8192];
      vim = w_im[b0 + 4096] + 2.f*w_im[b0 + 8192];
    }
    float q0 = imf ? vim : vre;
    float q1 = imf ? vre : -vim;
    row32[d] = f2bf(q0) | (f2bf(q1) << 16);
  }
  int s = ((i >> 3) ^ (o & 7)) & 7;
  int n = c*4096 + o*64 + s*8 + (i & 7);
  uint4* dst = (uint4*)((uint16_t*)((char*)ws + WS_RHS_B) + (size_t)n*64);
  #pragma unroll
  for (int j = 0; j < 4; ++j) {
    uint4 qv = make_uint4(row32[4*j], row32[4*j+1], row32[4*j+2], row32[4*j+3]);
    dst[j]     = qv;   // h=0
    dst[j + 4] = qv;   // h=1 duplicate (hi/lo ne split reconstructs fp32)
  }
}

// K3a: partial Gram, 25 blocks x 80 v
__global__ void k_norm1(const float* __restrict__ ne_re, const float* __restrict__ ne_im,
                        float* __restrict__ ws) {
  int t = threadIdx.x;
  int d = t >> 4, e = t & 15;
  int v0 = blockIdx.x * 80;
  float gr = 0.f, gi = 0.f;
  for (int v = v0; v < v0 + 80; ++v) {
    float ar = ne_re[v*DD + d], ai = ne_im[v*DD + d];
    float br = ne_re[v*DD + e], bi = ne_im[v*DD + e];
    gr += ar*br + ai*bi;
    gi += ar*bi - ai*br;
  }
  atomicAdd(ws + WS_GRAM_DW + 2*t,     gr);
  atomicAdd(ws + WS_GRAM_DW + 2*t + 1, gi);
}

// K3b: inv_norm
__global__ void k_norm2(float* __restrict__ ws) {
  int t = threadIdx.x;
  float gr = ws[WS_GRAM_DW + 2*t], gi = ws[WS_GRAM_DW + 2*t + 1];
  __shared__ float red[256];
  red[t] = gr*gr + gi*gi;
  __syncthreads();
  for (int k = 128; k > 0; k >>= 1) {
    if (t < k) red[t] += red[t + k];
    __syncthreads();
  }
  if (t == 0) ws[WS_INV_DW] = 1.0f / sqrtf(red[0]);
}

// K4: bias2[u][2*o+half] fp32 (interleaved so k_final stores are linear)
__global__ void k_bias(const float* __restrict__ ne_re, const float* __restrict__ ne_im,
                       const float* __restrict__ b_re, const float* __restrict__ b_im,
                       float* __restrict__ ws) {
  int gid = blockIdx.x * 256 + threadIdx.x;   // 1000 blocks -> 256000
  int u = gid >> 7, idx = gid & 127;
  int o = idx >> 1, half = idx & 1;
  float acc = 0.f;
  #pragma unroll
  for (int d = 0; d < DD; ++d) {
    float nr = ne_re[u*DD + d], ni = ne_im[u*DD + d];
    float pr = b_re[d*CO + o],  pi = b_im[d*CO + o];
    acc += half ? (nr*pi + ni*pr) : (nr*pr - ni*pi);
  }
  ws[WS_BIAS_DW + gid] = acc;
}

// K5: Z partials. grid 1024 = (b:64)x(chunk:16), block 256 = 4 waves x 64 lanes.
__global__ void __launch_bounds__(256, 4)
k_z(const float* __restrict__ x, const float* __restrict__ ne_re,
    const float* __restrict__ ne_im, float* __restrict__ ws) {
  int b = blockIdx.x >> 4, c = blockIdx.x & 15;
  int t = threadIdx.x, w = t >> 6, i = t & 63;
  __shared__ float sred[4 * 2048];

  float zr[DD], zi[DD];
  #pragma unroll
  for (int d = 0; d < DD; ++d) { zr[d] = 0.f; zi[d] = 0.f; }

  int vbase = c * 125;
  int v0 = vbase + ((w * 125) >> 2);
  int v1 = vbase + (((w + 1) * 125) >> 2);
  const float* xp = x + ((size_t)b * VV + v0) * CI + i;
  #pragma unroll 4
  for (int v = v0; v < v1; ++v) {
    float xv = *xp; xp += CI;
    #pragma unroll
    for (int d = 0; d < DD; ++d) {
      zr[d] += ne_re[v*DD + d] * xv;
      zi[d] -= ne_im[v*DD + d] * xv;
    }
  }
  #pragma unroll
  for (int d = 0; d < DD; ++d) {
    sred[w*2048 + d*128 + i*2 + 0] = zr[d];
    sred[w*2048 + d*128 + i*2 + 1] = zi[d];
  }
  __syncthreads();
  float* ZP = ws + WS_ZP_DW;
  #pragma unroll
  for (int k = 0; k < 8; ++k) {
    int j = t + k*256;
    float s = sred[j] + sred[2048 + j] + sred[4096 + j] + sred[6144 + j];
    int d = j >> 7, r = j & 127;
    ZP[(size_t)c*131072 + d*8192 + b*128 + r] = s;
  }
}

// K5b: Z = sum over 16 chunks of ZP
__global__ void k_zred(float* __restrict__ ws) {
  int g = blockIdx.x * 256 + threadIdx.x;
  const float2* ZP2 = (const float2*)(ws + WS_ZP_DW);
  float2 acc = make_float2(0.f, 0.f);
  #pragma unroll
  for (int c = 0; c < 16; ++c) {
    float2 v = ZP2[(size_t)c*65536 + g];
    acc.x += v.x; acc.y += v.y;
  }
  ((float2*)(ws + WS_Z_DW))[g] = acc;
}

// K6: W GEMM -> compact Wc[u][16384]. Interleaved n-tile pairs: tile t covers
// n = nb + 2*n16 + t, so each lane packs (n, n+1) -> dword -> 64B line stores.
__global__ void __launch_bounds__(256, 4)
k_wgemm(float* __restrict__ ws) {
  const uint16_t* NE  = (const uint16_t*)((char*)ws + WS_NE_B);
  const uint16_t* RHS = (const uint16_t*)((char*)ws + WS_RHS_B);
  uint32_t*       W   = (uint32_t*)((char*)ws + WS_W_B);
  int ut = blockIdx.x, nc = blockIdx.y;
  int t = threadIdx.x, w = t >> 6, lane = t & 63;
  int n16 = lane & 15, quad = lane >> 4;
  short8 a[4][2];
  #pragma unroll
  for (int m = 0; m < 4; ++m) {
    int u = ut*64 + m*16 + n16;
    a[m][0] = *(const short8*)(NE + u*64 + quad*8);
    a[m][1] = *(const short8*)(NE + u*64 + 32 + quad*8);
  }
  int nbase = nc*1024 + w*256;
  #pragma unroll 2
  for (int pt = 0; pt < 8; ++pt) {
    int nb = nbase + pt*32;
    const uint16_t* r0 = RHS + (size_t)(nb + 2*n16 + 0)*64 + quad*8;
    const uint16_t* r1 = RHS + (size_t)(nb + 2*n16 + 1)*64 + quad*8;
    short8 b00 = *(const short8*)r0;
    short8 b01 = *(const short8*)(r0 + 32);
    short8 b10 = *(const short8*)r1;
    short8 b11 = *(const short8*)(r1 + 32);
    #pragma unroll
    for (int m = 0; m < 4; ++m) {
      f32x4 acc0 = (f32x4){0.f,0.f,0.f,0.f};
      f32x4 acc1 = (f32x4){0.f,0.f,0.f,0.f};
      acc0 = __builtin_amdgcn_mfma_f32_16x16x32_bf16(a[m][0], b00, acc0, 0, 0, 0);
      acc0 = __builtin_amdgcn_mfma_f32_16x16x32_bf16(a[m][1], b01, acc0, 0, 0, 0);
      acc1 = __builtin_amdgcn_mfma_f32_16x16x32_bf16(a[m][0], b10, acc1, 0, 0, 0);
      acc1 = __builtin_amdgcn_mfma_f32_16x16x32_bf16(a[m][1], b11, acc1, 0, 0, 0);
      #pragma unroll
      for (int r = 0; r < 4; ++r) {
        int u = ut*64 + m*16 + quad*4 + r;
        if (u < VV) {
          uint32_t pk = f2bf(acc0[r]) | (f2bf(acc1[r]) << 16);
          W[(size_t)u*8192 + (nb >> 1) + n16] = pk;
        }
      }
    }
  }
}

// K7: compact U[u][3][64][64] (c: x, yr, yi; swizzle baked), LDS-staged stores.
// grid (125 ug, 16 by), block 256 = 4 b x 64 i, 16 u per block.
__global__ void __launch_bounds__(256, 4)
k_u(const float* __restrict__ x, const float* __restrict__ ne_re,
    const float* __restrict__ ne_im, float* __restrict__ ws) {
  int ug = blockIdx.x, by = blockIdx.y;
  int t = threadIdx.x, q = t >> 6, i = t & 63;
  int b = by*4 + q;
  float invn = ws[WS_INV_DW];
  const float* Z = ws + WS_Z_DW;
  float zr[DD], zi[DD];
  #pragma unroll
  for (int d = 0; d < DD; ++d) {
    const float* zp = Z + (size_t)(d*4096 + b*64 + i) * 2;
    zr[d] = zp[0]; zi[d] = zp[1];
  }
  __shared__ uint16_t sStage[192 * 64];       // rr = ul*12 + c*4 + q
  int bkey = b & 7;
  int pos = (((i >> 3) ^ bkey) & 7)*8 + (i & 7);
  for (int ul = 0; ul < 16; ++ul) {
    int u = ug*16 + ul;
    float yr = 0.f, yi = 0.f;
    #pragma unroll
    for (int d = 0; d < DD; ++d) {
      float nr = ne_re[u*DD + d], ni = ne_im[u*DD + d];
      yr += nr*zr[d] - ni*zi[d];
      yi += nr*zi[d] + ni*zr[d];
    }
    float xv = x[((size_t)b*VV + u)*CI + i];
    sStage[(ul*12 + 0 + q)*64 + pos] = (uint16_t)f2bf(xv);
    sStage[(ul*12 + 4 + q)*64 + pos] = (uint16_t)f2bf(yr * invn);
    sStage[(ul*12 + 8 + q)*64 + pos] = (uint16_t)f2bf(yi * invn);
  }
  __syncthreads();
  // flush: 192 rows x 128B, 32 rows per pass (8 lanes/row), 6 passes
  uint16_t* U = (uint16_t*)((char*)ws + WS_U_B);
  const uint4* sv = (const uint4*)sStage;
  #pragma unroll
  for (int pass = 0; pass < 6; ++pass) {
    int rr = pass*32 + (t >> 3), l8 = t & 7;
    int ul = rr / 12, rem = rr - ul*12;
    int c = rem >> 2, qq = rem & 3;
    uint4 v = sv[rr*8 + l8];
    *(uint4*)(U + (size_t)(ug*16 + ul)*12288 + c*4096 + (by*4 + qq)*64 + l8*8) = v;
  }
}

// K8: per-node MFMA from compact W,U. LDS pitch 80 elems (160B) -> <=2-way
// bank conflicts. Out stores: wave columns = (8 o)x(re,im) interleaved ->
// 16 consecutive dwords = 64B lines.
#define LP 80           // LDS row pitch (elems)
#define CSTRIDE 5120    // 64*LP: comp stride (elems)
__global__ void __launch_bounds__(512, 2)
k_final(const float* __restrict__ ws, float* __restrict__ out) {
  int u = blockIdx.x, t = threadIdx.x;
  __shared__ __align__(16) uint16_t sW[4 * CSTRIDE];   // 40960B
  __shared__ __align__(16) uint16_t sU[3 * CSTRIDE];   // 30720B
  const uint4* Wg = (const uint4*)((const char*)ws + WS_W_B + (size_t)u*32768);
  const uint4* Ug = (const uint4*)((const char*)ws + WS_U_B + (size_t)u*24576);
  #pragma unroll
  for (int j = 0; j < 4; ++j) {
    int idx = j*512 + t;                       // 2048 chunks of 16B
    int row = idx >> 3, col = idx & 7;
    *(uint4*)&sW[row*LP + col*8] = Wg[idx];
  }
  #pragma unroll
  for (int j = 0; j < 3; ++j) {
    int idx = j*512 + t;                       // 1536 chunks
    int row = idx >> 3, col = idx & 7;
    *(uint4*)&sU[row*LP + col*8] = Ug[idx];
  }
  __syncthreads();

  int w = t >> 6, lane = t & 63;
  int n16 = lane & 15, quad = lane >> 4;
  int o = w*8 + (n16 >> 1), half = n16 & 1;
  int okey = o & 7;
  uint32_t sgnmask = half ? 0u : 0x80008000u;  // negate Bi for re-half at cb=2
  f32x4 acc[4];
  #pragma unroll
  for (int m = 0; m < 4; ++m) acc[m] = (f32x4){0.f,0.f,0.f,0.f};

  #pragma unroll
  for (int ks = 0; ks < 6; ++ks) {
    int cb = ks >> 1;                          // 0,0,1,1,2,2
    int i8 = (ks & 1)*4 + quad;                // logical granule & 7
    int c  = (cb == 0) ? half : ((cb == 1) ? 2 + half : 3 - half);
    int slot = (i8 ^ okey) & 7;
    short8 bfrag = *(const short8*)&sW[c*CSTRIDE + o*LP + slot*8];
    if (cb == 2) {
      uint32_t* bu = (uint32_t*)&bfrag;
      #pragma unroll
      for (int jj = 0; jj < 4; ++jj) bu[jj] ^= sgnmask;
    }
    #pragma unroll
    for (int m = 0; m < 4; ++m) {
      int b = m*16 + n16;
      int aslot = (i8 ^ (b & 7)) & 7;
      short8 afrag = *(const short8*)&sU[cb*CSTRIDE + b*LP + aslot*8];
      acc[m] = __builtin_amdgcn_mfma_f32_16x16x32_bf16(afrag, bfrag, acc[m], 0, 0, 0);
    }
  }

  float bias = ws[WS_BIAS_DW + u*128 + w*16 + n16];
  #pragma unroll
  for (int m = 0; m < 4; ++m) {
    #pragma unroll
    for (int r = 0; r < 4; ++r) {
      int b = m*16 + quad*4 + r;
      out[((size_t)b*VV + u)*128 + w*16 + n16] = acc[m][r] + bias;
    }
  }
}

// ---------------------------------------------------------------------------
extern "C" void kernel_launch(void* const* d_in, const int* in_sizes, int n_in,
                              void* d_out, int out_size, void* d_ws, size_t ws_size,
                              hipStream_t stream) {
  (void)in_sizes; (void)n_in; (void)out_size; (void)ws_size;
  const float* x     = (const float*)d_in[0];
  const float* ne_re = (const float*)d_in[1];
  const float* ne_im = (const float*)d_in[2];
  const float* w_re  = (const float*)d_in[3];
  const float* w_im  = (const float*)d_in[4];
  const float* b_re  = (const float*)d_in[5];
  const float* b_im  = (const float*)d_in[6];
  float* out = (float*)d_out;
  float* ws  = (float*)d_ws;

  k_zero <<<dim3(1),          dim3(256), 0, stream>>>(ws);
  k_ne   <<<dim3(512),        dim3(256), 0, stream>>>(ne_re, ne_im, ws);
  k_rhs  <<<dim3(64),         dim3(256), 0, stream>>>(w_re, w_im, ws);
  k_norm1<<<dim3(25),         dim3(256), 0, stream>>>(ne_re, ne_im, ws);
  k_norm2<<<dim3(1),          dim3(256), 0, stream>>>(ws);
  k_bias <<<dim3(1000),       dim3(256), 0, stream>>>(ne_re, ne_im, b_re, b_im, ws);
  k_z    <<<dim3(1024),       dim3(256), 0, stream>>>(x, ne_re, ne_im, ws);
  k_zred <<<dim3(256),        dim3(256), 0, stream>>>(ws);
  k_wgemm<<<dim3(32, 16),     dim3(256), 0, stream>>>(ws);
  k_u    <<<dim3(125, 16),    dim3(256), 0, stream>>>(x, ne_re, ne_im, ws);
  k_final<<<dim3(VV),         dim3(512), 0, stream>>>(ws, out);
}